// Round 1
// 1318.355 us; speedup vs baseline: 1.0086x; 1.0086x over previous
//
#include <hip/hip_runtime.h>
#include <math.h>

#define N_NODES 100000
#define N_EDGES 3200000
#define IN_DIM  500
#define HID     64
#define OUT_DIM 40
#define K_ITERS 10
#define ALPHA   0.1f
#define BN_EPS  1e-5f

#define WPAD 48        // padded dim for lin1 compute tile (Wc columns)
#define YD   40        // stored propagation dim (fp32 stride, floats)
#define YH   20        // bf16-packed row stride (u32 words)
#define NBUCK 782      // ceil(100000/128), bucket = dest >> 7
#define TILE_A 8192    // edges per bucketA block
#define APG 48         // nodes per appnp block (4 waves x 12 nodes)

// ---------------- bf16 helpers ----------------
__device__ __forceinline__ void unpack8(uint4 v, float f[8]) {
    f[0] = __uint_as_float(v.x << 16);
    f[1] = __uint_as_float(v.x & 0xffff0000u);
    f[2] = __uint_as_float(v.y << 16);
    f[3] = __uint_as_float(v.y & 0xffff0000u);
    f[4] = __uint_as_float(v.z << 16);
    f[5] = __uint_as_float(v.z & 0xffff0000u);
    f[6] = __uint_as_float(v.w << 16);
    f[7] = __uint_as_float(v.w & 0xffff0000u);
}
__device__ __forceinline__ unsigned pack2(float a, float b) {   // RNE bf16 pair
    unsigned ua = __float_as_uint(a);
    unsigned ub = __float_as_uint(b);
    ua += ((ua >> 16) & 1u) + 0x7fffu;
    ub += ((ub >> 16) & 1u) + 0x7fffu;
    return (ua >> 16) | (ub & 0xffff0000u);
}
// packed edge: low 17 bits = src idx, high 15 bits = weight (f32 bits >> 16, sign 0)
__device__ __forceinline__ float edge_w(unsigned e) {
    return __uint_as_float((e >> 17) << 16);
}
__device__ __forceinline__ void fma8(float acc[8], float wgt, const float f[8]) {
#pragma unroll
    for (int i = 0; i < 8; ++i) acc[i] = fmaf(wgt, f[i], acc[i]);
}

// ---------------- degree histogram + scan ----------------

__global__ void zero_cnt_kernel(int* __restrict__ cnt) {
    int i = blockIdx.x * 256 + threadIdx.x;
    if (i < N_NODES) cnt[i] = 0;
}

__global__ void hist_kernel(const int* __restrict__ ei, int* __restrict__ cnt) {
    int e = blockIdx.x * 256 + threadIdx.x;
    if (e < N_EDGES) atomicAdd(&cnt[ei[N_EDGES + e]], 1);  // col = ei[1][e]
}

__global__ void reduce_kernel(const int* __restrict__ cnt, int* __restrict__ psum) {
    __shared__ int s[256];
    int i = blockIdx.x * 256 + threadIdx.x;
    int v = (i < N_NODES) ? cnt[i] : 0;
    s[threadIdx.x] = v;
    __syncthreads();
    for (int off = 128; off > 0; off >>= 1) {
        if (threadIdx.x < (unsigned)off) s[threadIdx.x] += s[threadIdx.x + off];
        __syncthreads();
    }
    if (threadIdx.x == 0) psum[blockIdx.x] = s[0];
}

__global__ void scanp_kernel(const int* __restrict__ psum, int* __restrict__ pexcl,
                             int nparts) {
    __shared__ int s[512];
    int t = threadIdx.x;
    int v = (t < nparts) ? psum[t] : 0;
    s[t] = v;
    __syncthreads();
    for (int off = 1; off < 512; off <<= 1) {
        int tv = (t >= off) ? s[t - off] : 0;
        __syncthreads();
        s[t] += tv;
        __syncthreads();
    }
    if (t < nparts) pexcl[t] = s[t] - v;
}

__global__ void apply_kernel(const int* __restrict__ cnt, const int* __restrict__ pexcl,
                             int* __restrict__ rowptr, float* __restrict__ dinv) {
    __shared__ int s[256];
    int t = threadIdx.x;
    int i = blockIdx.x * 256 + t;
    int v = (i < N_NODES) ? cnt[i] : 0;
    s[t] = v;
    __syncthreads();
    for (int off = 1; off < 256; off <<= 1) {
        int tv = (t >= off) ? s[t - off] : 0;
        __syncthreads();
        s[t] += tv;
        __syncthreads();
    }
    if (i < N_NODES) {
        int excl = pexcl[blockIdx.x] + s[t] - v;
        rowptr[i] = excl;
        dinv[i] = rsqrtf((float)(v + 1));        // +1 self-loop; always > 0
        if (i == N_NODES - 1) rowptr[N_NODES] = excl + v;
    }
}

// ---------------- bucketed two-phase fill ----------------

__global__ void bcur_init_kernel(const int* __restrict__ rowptr, int* __restrict__ bcursor) {
    int i = blockIdx.x * 256 + threadIdx.x;
    if (i < NBUCK) bcursor[i] = rowptr[i << 7];
}

// Phase A: partition edges into 782 dest-buckets; payload = src(17b) | c_local(7b)
__global__ __launch_bounds__(256) void bucketA_kernel(const int* __restrict__ ei,
                                                      int* __restrict__ bcursor,
                                                      unsigned* __restrict__ ebuf) {
    __shared__ int cnt[NBUCK];
    __shared__ int gbase[NBUCK];
    for (int i = threadIdx.x; i < NBUCK; i += 256) cnt[i] = 0;
    __syncthreads();
    const int e0 = blockIdx.x * TILE_A;
    const int e1 = (e0 + TILE_A < N_EDGES) ? e0 + TILE_A : N_EDGES;
    for (int e = e0 + threadIdx.x; e < e1; e += 256)
        atomicAdd(&cnt[ei[N_EDGES + e] >> 7], 1);
    __syncthreads();
    for (int i = threadIdx.x; i < NBUCK; i += 256) {
        int n = cnt[i];
        gbase[i] = (n > 0) ? atomicAdd(&bcursor[i], n) : 0;
        cnt[i] = 0;     // reuse as rank counter
    }
    __syncthreads();
    for (int e = e0 + threadIdx.x; e < e1; e += 256) {
        int r = ei[e];
        int c = ei[N_EDGES + e];
        int b = c >> 7;
        int rank = atomicAdd(&cnt[b], 1);
        ebuf[gbase[b] + rank] = (unsigned)r | ((unsigned)(c & 127) << 17);
    }
}

// Phase B: one block per bucket; node cursors in LDS; write packed (src|w) CSR
__global__ __launch_bounds__(256) void bucketB_kernel(const unsigned* __restrict__ ebuf,
                                                      const int* __restrict__ rowptr,
                                                      const float* __restrict__ dinv,
                                                      unsigned* __restrict__ ew) {
    __shared__ int lcur[128];
    __shared__ float ldinv[128];
    const int base = blockIdx.x << 7;
    const int nn = (N_NODES - base < 128) ? (N_NODES - base) : 128;
    if (threadIdx.x < (unsigned)nn) {
        lcur[threadIdx.x] = rowptr[base + threadIdx.x];
        ldinv[threadIdx.x] = dinv[base + threadIdx.x];
    }
    __syncthreads();
    const int s0 = rowptr[base];
    const int hi = (base + 128 < N_NODES) ? base + 128 : N_NODES;
    const int s1 = rowptr[hi];
    for (int p = s0 + threadIdx.x; p < s1; p += 256) {
        unsigned v = ebuf[p];
        int r = v & 0x1ffff;
        int cl = v >> 17;
        int pos = atomicAdd(&lcur[cl], 1);
        float w = dinv[r] * ldinv[cl];
        unsigned f = __float_as_uint(w) + 0x8000u;   // round-half-up to e8m7
        ew[pos] = (unsigned)r | ((f >> 16) << 17);
    }
}

// ---------------- fold BN+W2 into propagation space ----------------
__global__ void prep_kernel(const float* __restrict__ W2, const float* __restrict__ gamma,
                            const float* __restrict__ beta, const float* __restrict__ mean,
                            const float* __restrict__ var, const float* __restrict__ b1,
                            const float* __restrict__ b2, float* __restrict__ W2p,
                            float* __restrict__ c1, float* __restrict__ cbeta) {
    __shared__ float sc[64];
    __shared__ float sd[64];
    int t = threadIdx.x;
    if (t < 64) {
        float s = rsqrtf(var[t] + BN_EPS) * gamma[t];
        sc[t] = s;
        sd[t] = beta[t] - mean[t] * s;
    }
    __syncthreads();
    for (int i = t; i < 64 * OUT_DIM; i += 256) {
        int f = i / OUT_DIM;
        W2p[i] = sc[f] * W2[i];
    }
    if (t < WPAD) {
        if (t < OUT_DIM) {
            float acb = b2[t], ac1 = 0.f;
            for (int f = 0; f < 64; ++f) {
                float w2 = W2[f * OUT_DIM + t];
                acb = fmaf(sd[f], w2, acb);
                ac1 = fmaf(b1[f] * sc[f], w2, ac1);
            }
            cbeta[t] = acb;
            c1[t] = ac1;
        } else {
            c1[t] = 0.f;
        }
    }
}

__global__ __launch_bounds__(256) void wc_kernel(const float* __restrict__ W1,
                                                 const float* __restrict__ W2p,
                                                 float* __restrict__ Wc) {
    __shared__ float w2s[64 * OUT_DIM];
    for (int i = threadIdx.x; i < 64 * OUT_DIM; i += 256) w2s[i] = W2p[i];
    __syncthreads();
    int idx = blockIdx.x * 256 + threadIdx.x;
    if (idx >= IN_DIM * WPAD) return;
    int k = idx / WPAD, o = idx % WPAD;
    float a = 0.f;
    if (o < OUT_DIM) {
        const float* w1r = W1 + (size_t)k * HID;
#pragma unroll 8
        for (int f = 0; f < 64; ++f) a = fmaf(w1r[f], w2s[f * OUT_DIM + o], a);
    }
    Wc[idx] = a;
}

// ---------------- y0 = x @ Wc + c1 ----------------
#define L1_M  128
#define L1_KC 20
#define L1_PITCH 132
__global__ __launch_bounds__(256) void lin1_kernel(const float* __restrict__ x,
                                                   const float* __restrict__ Wc,
                                                   const float* __restrict__ c1,
                                                   float* __restrict__ y0f,
                                                   unsigned* __restrict__ y0b) {
    __shared__ float xsT[L1_KC * L1_PITCH];
    __shared__ float wcs[L1_KC * WPAD];

    const int t = threadIdx.x;
    const int ng = t & 31;
    const int og = t >> 5;
    const int nbase = blockIdx.x * L1_M;

    const int srow = t >> 1;
    const int skb  = (t & 1) * 10;
    const int gsrc = nbase + srow;
    const int gcl  = (gsrc < N_NODES) ? gsrc : (N_NODES - 1);
    const float* xrow = x + (size_t)gcl * IN_DIM;

    float acc[4][6];
#pragma unroll
    for (int i = 0; i < 4; ++i)
#pragma unroll
        for (int j = 0; j < 6; ++j) acc[i][j] = 0.0f;

    for (int k0 = 0; k0 < IN_DIM; k0 += L1_KC) {
        __syncthreads();
#pragma unroll
        for (int u = 0; u < 5; ++u) {
            const float2 xv = *(const float2*)(xrow + k0 + skb + 2 * u);
            xsT[(skb + 2 * u) * L1_PITCH + srow]     = xv.x;
            xsT[(skb + 2 * u + 1) * L1_PITCH + srow] = xv.y;
        }
        for (int i = t; i < L1_KC * WPAD; i += 256) wcs[i] = Wc[(size_t)k0 * WPAD + i];
        __syncthreads();

#pragma unroll 4
        for (int k = 0; k < L1_KC; ++k) {
            const float4 xv = *(const float4*)&xsT[k * L1_PITCH + ng * 4];
            float w[6];
#pragma unroll
            for (int j = 0; j < 6; ++j) w[j] = wcs[k * WPAD + og * 6 + j];
            const float xr[4] = {xv.x, xv.y, xv.z, xv.w};
#pragma unroll
            for (int i = 0; i < 4; ++i)
#pragma unroll
                for (int j = 0; j < 6; ++j)
                    acc[i][j] = fmaf(xr[i], w[j], acc[i][j]);
        }
    }

    float cc[6];
#pragma unroll
    for (int j = 0; j < 6; ++j) cc[j] = c1[og * 6 + j];
#pragma unroll
    for (int i = 0; i < 4; ++i) {
        const int n = nbase + ng * 4 + i;
        if (n < N_NODES) {
            float o[6];
#pragma unroll
            for (int j = 0; j < 6; ++j) o[j] = acc[i][j] + cc[j];
            // dims covered: og*6 .. og*6+5 ; only dims < 40 are stored
            float* yf = y0f + (size_t)n * YD + og * 6;
            unsigned* yb = y0b + (size_t)n * YH + og * 3;
            if (og < 6) {
                *(float2*)(yf)     = make_float2(o[0], o[1]);
                *(float2*)(yf + 2) = make_float2(o[2], o[3]);
                *(float2*)(yf + 4) = make_float2(o[4], o[5]);
                yb[0] = pack2(o[0], o[1]);
                yb[1] = pack2(o[2], o[3]);
                yb[2] = pack2(o[4], o[5]);
            } else if (og == 6) {   // dims 36..39 valid, 40..41 are pad
                *(float2*)(yf)     = make_float2(o[0], o[1]);
                *(float2*)(yf + 2) = make_float2(o[2], o[3]);
                yb[0] = pack2(o[0], o[1]);
                yb[1] = pack2(o[2], o[3]);
            }
            // og == 7: dims 42..47, all pad — nothing stored
        }
    }
}

// ---------------- APPNP step (40-dim, bf16 uint4 gather, fp32 accumulate) ----------
// 5 lanes per node (8 dims/lane via one uint4 = 8 bf16), 12 nodes per wave
// (60/64 lanes active), 4 waves per block -> 48 nodes/block.
template <bool LAST>
__global__ __launch_bounds__(256) void appnp40_kernel(const int* __restrict__ rowptr,
                                                      const unsigned* __restrict__ ew,
                                                      const float* __restrict__ dinv,
                                                      const unsigned* __restrict__ yin,
                                                      const float* __restrict__ h,
                                                      unsigned* __restrict__ yout,
                                                      float* __restrict__ yKf) {
    const int wv   = threadIdx.x >> 6;      // wave 0..3
    const int lane = threadIdx.x & 63;
    const int sub  = lane / 5;              // 0..12 (12 -> inactive)
    const int dl   = lane - sub * 5;        // 0..4
    const int node = blockIdx.x * APG + wv * 12 + sub;
    const bool act = (lane < 60) && (node < N_NODES);
    const int dl4  = dl * 4;                // u32-word offset within row

    int beg = 0, end = 0;
    float selfw = 0.f;
    if (act) {
        beg = rowptr[node];
        end = rowptr[node + 1];
        const float di = dinv[node];
        selfw = di * di;
    }

    // issue the per-node loads early so they overlap the edge loop
    uint4 vs = make_uint4(0, 0, 0, 0);
    float4 h0 = make_float4(0.f, 0.f, 0.f, 0.f), h1 = h0;
    if (act) {
        vs = *(const uint4*)(yin + (size_t)node * YH + dl4);
        h0 = *(const float4*)(h + (size_t)node * YD + dl * 8);
        h1 = *(const float4*)(h + (size_t)node * YD + dl * 8 + 4);
    }

    float acc[8];
#pragma unroll
    for (int i = 0; i < 8; ++i) acc[i] = 0.f;

    int p = beg;
    for (; p + 3 < end; p += 4) {
        const unsigned e0 = ew[p], e1 = ew[p + 1], e2 = ew[p + 2], e3 = ew[p + 3];
        const uint4 v0 = *(const uint4*)(yin + (size_t)(e0 & 0x1ffff) * YH + dl4);
        const uint4 v1 = *(const uint4*)(yin + (size_t)(e1 & 0x1ffff) * YH + dl4);
        const uint4 v2 = *(const uint4*)(yin + (size_t)(e2 & 0x1ffff) * YH + dl4);
        const uint4 v3 = *(const uint4*)(yin + (size_t)(e3 & 0x1ffff) * YH + dl4);
        float f[8];
        unpack8(v0, f); fma8(acc, edge_w(e0), f);
        unpack8(v1, f); fma8(acc, edge_w(e1), f);
        unpack8(v2, f); fma8(acc, edge_w(e2), f);
        unpack8(v3, f); fma8(acc, edge_w(e3), f);
    }
    for (; p < end; ++p) {
        const unsigned e0 = ew[p];
        const uint4 v0 = *(const uint4*)(yin + (size_t)(e0 & 0x1ffff) * YH + dl4);
        float f[8];
        unpack8(v0, f);
        fma8(acc, edge_w(e0), f);
    }

    if (act) {
        float fs[8];
        unpack8(vs, fs);
        const float ha[8] = {h0.x, h0.y, h0.z, h0.w, h1.x, h1.y, h1.z, h1.w};
        float o[8];
#pragma unroll
        for (int i = 0; i < 8; ++i)
            o[i] = (1.0f - ALPHA) * fmaf(selfw, fs[i], acc[i]) + ALPHA * ha[i];
        if (LAST) {
            *(float4*)(yKf + (size_t)node * YD + dl * 8)     = make_float4(o[0], o[1], o[2], o[3]);
            *(float4*)(yKf + (size_t)node * YD + dl * 8 + 4) = make_float4(o[4], o[5], o[6], o[7]);
        } else {
            uint4 w;
            w.x = pack2(o[0], o[1]);
            w.y = pack2(o[2], o[3]);
            w.z = pack2(o[4], o[5]);
            w.w = pack2(o[6], o[7]);
            *(uint4*)(yout + (size_t)node * YH + dl4) = w;
        }
    }
}

// ---------------- emb = yK + cbeta; log_softmax ----------------
__global__ __launch_bounds__(256) void final_kernel(const float* __restrict__ yKf,
                                                    const float* __restrict__ cbeta,
                                                    float* __restrict__ out_ls,
                                                    float* __restrict__ out_emb) {
    const int lane = threadIdx.x & 63;
    const int wv   = threadIdx.x >> 6;
    const int node = blockIdx.x * 4 + wv;

    float e = 0.0f;
    if (lane < OUT_DIM) e = yKf[(size_t)node * YD + lane] + cbeta[lane];
    float ev = (lane < OUT_DIM) ? e : -INFINITY;
    float m = ev;
#pragma unroll
    for (int off = 32; off > 0; off >>= 1) m = fmaxf(m, __shfl_xor(m, off, 64));
    float p = (lane < OUT_DIM) ? expf(ev - m) : 0.0f;
    float s = p;
#pragma unroll
    for (int off = 32; off > 0; off >>= 1) s += __shfl_xor(s, off, 64);
    if (lane < OUT_DIM) {
        float ls = ev - m - logf(s);
        out_ls[(size_t)node * OUT_DIM + lane] = ls;
        out_emb[(size_t)node * OUT_DIM + lane] = e;
    }
}

// ---------------- launch ----------------

extern "C" void kernel_launch(void* const* d_in, const int* in_sizes, int n_in,
                              void* d_out, int out_size, void* d_ws, size_t ws_size,
                              hipStream_t stream) {
    const float* x     = (const float*)d_in[0];
    const int*   ei    = (const int*)d_in[1];
    const float* W1    = (const float*)d_in[2];
    const float* b1    = (const float*)d_in[3];
    const float* gamma = (const float*)d_in[4];
    const float* beta  = (const float*)d_in[5];
    const float* mean  = (const float*)d_in[6];
    const float* var   = (const float*)d_in[7];
    const float* W2    = (const float*)d_in[8];
    const float* b2    = (const float*)d_in[9];

    char* ws = (char*)d_ws;
    size_t off = 0;
    auto alloc = [&](size_t bytes) { char* p = ws + off; off += (bytes + 255) & ~(size_t)255; return p; };

    unsigned* ew     = (unsigned*)alloc((size_t)N_EDGES * 4);          // 12.8 MB
    unsigned* ebuf   = (unsigned*)alloc((size_t)N_EDGES * 4);          // 12.8 MB
    float*    y0f    = (float*)   alloc((size_t)N_NODES * YD * 4);     // 16 MB
    float*    yKf    = (float*)   alloc((size_t)N_NODES * YD * 4);     // 16 MB
    unsigned* y0b    = (unsigned*)alloc((size_t)N_NODES * YH * 4);     // 8 MB
    unsigned* ya     = (unsigned*)alloc((size_t)N_NODES * YH * 4);
    unsigned* yb     = (unsigned*)alloc((size_t)N_NODES * YH * 4);
    float*    Wc     = (float*)   alloc((size_t)IN_DIM * WPAD * 4);
    float*    W2p    = (float*)   alloc(64 * OUT_DIM * 4);
    float*    c1     = (float*)   alloc(WPAD * 4);
    float*    cbeta  = (float*)   alloc(OUT_DIM * 4);
    int*      cnt    = (int*)     alloc(N_NODES * 4);
    float*    dinv   = (float*)   alloc(N_NODES * 4);
    int*      rowptr = (int*)     alloc((N_NODES + 1) * 4);
    int*      bcursor= (int*)     alloc(NBUCK * 4);
    int*      psum   = (int*)     alloc(1600 * 4);
    int*      pexcl  = (int*)     alloc(1600 * 4);

    float* out_ls  = (float*)d_out;
    float* out_emb = (float*)d_out + (size_t)N_NODES * OUT_DIM;

    const int NB_N = (N_NODES + 255) / 256;   // 391
    const int NB_E = (N_EDGES + 255) / 256;   // 12500
    const int NB_A = (N_EDGES + TILE_A - 1) / TILE_A;  // 391
    const int NB_P = (N_NODES + APG - 1) / APG;        // 2084

    zero_cnt_kernel<<<NB_N, 256, 0, stream>>>(cnt);
    hist_kernel<<<NB_E, 256, 0, stream>>>(ei, cnt);
    reduce_kernel<<<NB_N, 256, 0, stream>>>(cnt, psum);
    scanp_kernel<<<1, 512, 0, stream>>>(psum, pexcl, NB_N);
    apply_kernel<<<NB_N, 256, 0, stream>>>(cnt, pexcl, rowptr, dinv);
    bcur_init_kernel<<<(NBUCK + 255) / 256, 256, 0, stream>>>(rowptr, bcursor);
    bucketA_kernel<<<NB_A, 256, 0, stream>>>(ei, bcursor, ebuf);
    bucketB_kernel<<<NBUCK, 256, 0, stream>>>(ebuf, rowptr, dinv, ew);

    prep_kernel<<<1, 256, 0, stream>>>(W2, gamma, beta, mean, var, b1, b2, W2p, c1, cbeta);
    wc_kernel<<<(IN_DIM * WPAD + 255) / 256, 256, 0, stream>>>(W1, W2p, Wc);
    lin1_kernel<<<(N_NODES + L1_M - 1) / L1_M, 256, 0, stream>>>(x, Wc, c1, y0f, y0b);

    const unsigned* cur = y0b;
    unsigned* nxt = ya;
    unsigned* buf[2] = {ya, yb};
    for (int k = 0; k < K_ITERS - 1; ++k) {
        appnp40_kernel<false><<<NB_P, 256, 0, stream>>>(rowptr, ew, dinv, cur,
                                                        y0f, nxt, nullptr);
        cur = nxt;
        nxt = buf[(k + 1) & 1];
    }
    appnp40_kernel<true><<<NB_P, 256, 0, stream>>>(rowptr, ew, dinv, cur,
                                                   y0f, nullptr, yKf);

    final_kernel<<<N_NODES / 4, 256, 0, stream>>>(yKf, cbeta, out_ls, out_emb);
}

// Round 2
// 1170.743 us; speedup vs baseline: 1.1358x; 1.1261x over previous
//
#include <hip/hip_runtime.h>
#include <math.h>

#define N_NODES 100000
#define N_EDGES 3200000
#define IN_DIM  500
#define HID     64
#define OUT_DIM 40
#define K_ITERS 10
#define ALPHA   0.1f
#define BN_EPS  1e-5f

#define WPAD 48        // padded dim for lin1 compute tile (Wc columns)
#define YD   40        // stored propagation dim (fp32 stride, floats)
#define YH   20        // bf16-packed row stride (u32 words)
#define NBUCK 782      // ceil(100000/128), bucket = dest >> 7
#define TILE_A 8192    // edges per bucketA block
#define APG 48         // nodes per appnp block (4 waves x 12 nodes)
#define NQ 8           // source-locality buckets (src >> 14)
#define QSHIFT 14

// ---------------- bf16 helpers ----------------
__device__ __forceinline__ void unpack8(uint4 v, float f[8]) {
    f[0] = __uint_as_float(v.x << 16);
    f[1] = __uint_as_float(v.x & 0xffff0000u);
    f[2] = __uint_as_float(v.y << 16);
    f[3] = __uint_as_float(v.y & 0xffff0000u);
    f[4] = __uint_as_float(v.z << 16);
    f[5] = __uint_as_float(v.z & 0xffff0000u);
    f[6] = __uint_as_float(v.w << 16);
    f[7] = __uint_as_float(v.w & 0xffff0000u);
}
__device__ __forceinline__ unsigned pack2(float a, float b) {   // RNE bf16 pair
    unsigned ua = __float_as_uint(a);
    unsigned ub = __float_as_uint(b);
    ua += ((ua >> 16) & 1u) + 0x7fffu;
    ub += ((ub >> 16) & 1u) + 0x7fffu;
    return (ua >> 16) | (ub & 0xffff0000u);
}
// packed edge: low 17 bits = src idx, high 15 bits = weight (f32 bits >> 16, sign 0)
__device__ __forceinline__ float edge_w(unsigned e) {
    return __uint_as_float((e >> 17) << 16);
}
__device__ __forceinline__ void fma8(float acc[8], float wgt, const float f[8]) {
#pragma unroll
    for (int i = 0; i < 8; ++i) acc[i] = fmaf(wgt, f[i], acc[i]);
}

// ---------------- degree histogram (per source-eighth) + scan ----------------

__global__ void zero_cnt_kernel(int* __restrict__ cntq) {
    int i = blockIdx.x * 256 + threadIdx.x;
    if (i < NQ * N_NODES) cntq[i] = 0;
}

__global__ void hist_kernel(const int* __restrict__ ei, int* __restrict__ cntq) {
    int e = blockIdx.x * 256 + threadIdx.x;
    if (e < N_EDGES) {
        int r = ei[e];                 // src
        int c = ei[N_EDGES + e];       // dst
        atomicAdd(&cntq[(r >> QSHIFT) * N_NODES + c], 1);
    }
}

__global__ void reduce_kernel(const int* __restrict__ cntq, int* __restrict__ psum) {
    __shared__ int s[256];
    int i = blockIdx.x * 256 + threadIdx.x;
    int v = 0;
    if (i < N_NODES) {
#pragma unroll
        for (int q = 0; q < NQ; ++q) v += cntq[q * N_NODES + i];
    }
    s[threadIdx.x] = v;
    __syncthreads();
    for (int off = 128; off > 0; off >>= 1) {
        if (threadIdx.x < (unsigned)off) s[threadIdx.x] += s[threadIdx.x + off];
        __syncthreads();
    }
    if (threadIdx.x == 0) psum[blockIdx.x] = s[0];
}

__global__ void scanp_kernel(const int* __restrict__ psum, int* __restrict__ pexcl,
                             int nparts) {
    __shared__ int s[512];
    int t = threadIdx.x;
    int v = (t < nparts) ? psum[t] : 0;
    s[t] = v;
    __syncthreads();
    for (int off = 1; off < 512; off <<= 1) {
        int tv = (t >= off) ? s[t - off] : 0;
        __syncthreads();
        s[t] += tv;
        __syncthreads();
    }
    if (t < nparts) pexcl[t] = s[t] - v;
}

__global__ void apply_kernel(const int* __restrict__ cntq, const int* __restrict__ pexcl,
                             int* __restrict__ rowptr, float* __restrict__ dinv) {
    __shared__ int s[256];
    int t = threadIdx.x;
    int i = blockIdx.x * 256 + t;
    int v = 0;
    if (i < N_NODES) {
#pragma unroll
        for (int q = 0; q < NQ; ++q) v += cntq[q * N_NODES + i];
    }
    s[t] = v;
    __syncthreads();
    for (int off = 1; off < 256; off <<= 1) {
        int tv = (t >= off) ? s[t - off] : 0;
        __syncthreads();
        s[t] += tv;
        __syncthreads();
    }
    if (i < N_NODES) {
        int excl = pexcl[blockIdx.x] + s[t] - v;
        rowptr[i] = excl;
        dinv[i] = rsqrtf((float)(v + 1));        // +1 self-loop; always > 0
        if (i == N_NODES - 1) rowptr[N_NODES] = excl + v;
    }
}

// ---------------- bucketed two-phase fill ----------------

__global__ void bcur_init_kernel(const int* __restrict__ rowptr, int* __restrict__ bcursor) {
    int i = blockIdx.x * 256 + threadIdx.x;
    if (i < NBUCK) bcursor[i] = rowptr[i << 7];
}

// Phase A: partition edges into 782 dest-buckets; payload = src(17b) | c_local(7b)
__global__ __launch_bounds__(256) void bucketA_kernel(const int* __restrict__ ei,
                                                      int* __restrict__ bcursor,
                                                      unsigned* __restrict__ ebuf) {
    __shared__ int cnt[NBUCK];
    __shared__ int gbase[NBUCK];
    for (int i = threadIdx.x; i < NBUCK; i += 256) cnt[i] = 0;
    __syncthreads();
    const int e0 = blockIdx.x * TILE_A;
    const int e1 = (e0 + TILE_A < N_EDGES) ? e0 + TILE_A : N_EDGES;
    for (int e = e0 + threadIdx.x; e < e1; e += 256)
        atomicAdd(&cnt[ei[N_EDGES + e] >> 7], 1);
    __syncthreads();
    for (int i = threadIdx.x; i < NBUCK; i += 256) {
        int n = cnt[i];
        gbase[i] = (n > 0) ? atomicAdd(&bcursor[i], n) : 0;
        cnt[i] = 0;     // reuse as rank counter
    }
    __syncthreads();
    for (int e = e0 + threadIdx.x; e < e1; e += 256) {
        int r = ei[e];
        int c = ei[N_EDGES + e];
        int b = c >> 7;
        int rank = atomicAdd(&cnt[b], 1);
        ebuf[gbase[b] + rank] = (unsigned)r | ((unsigned)(c & 127) << 17);
    }
}

// Phase B: one block per bucket; per-node per-eighth cursors in LDS.
// Each node's CSR segment is partitioned by source eighth (src >> 14) so the
// APPNP gather sweeps source rows in ~1.3 MB windows that stay L2-resident.
__global__ __launch_bounds__(256) void bucketB_kernel(const unsigned* __restrict__ ebuf,
                                                      const int* __restrict__ rowptr,
                                                      const int* __restrict__ cntq,
                                                      const float* __restrict__ dinv,
                                                      unsigned* __restrict__ ew) {
    __shared__ int lcur[NQ * 128];
    __shared__ float ldinv[128];
    const int base = blockIdx.x << 7;
    const int nn = (N_NODES - base < 128) ? (N_NODES - base) : 128;
    if (threadIdx.x < (unsigned)nn) {
        const int gi = base + threadIdx.x;
        int run = rowptr[gi];
#pragma unroll
        for (int q = 0; q < NQ; ++q) {
            lcur[q * 128 + threadIdx.x] = run;
            run += cntq[q * N_NODES + gi];
        }
        ldinv[threadIdx.x] = dinv[gi];
    }
    __syncthreads();
    const int s0 = rowptr[base];
    const int hi = (base + 128 < N_NODES) ? base + 128 : N_NODES;
    const int s1 = rowptr[hi];
    for (int p = s0 + threadIdx.x; p < s1; p += 256) {
        unsigned v = ebuf[p];
        int r = v & 0x1ffff;
        int cl = v >> 17;
        int q = r >> QSHIFT;
        int pos = atomicAdd(&lcur[q * 128 + cl], 1);
        float w = dinv[r] * ldinv[cl];
        unsigned f = __float_as_uint(w) + 0x8000u;   // round-half-up to e8m7
        ew[pos] = (unsigned)r | ((f >> 16) << 17);
    }
}

// ---------------- fold BN+W2 into propagation space ----------------
__global__ void prep_kernel(const float* __restrict__ W2, const float* __restrict__ gamma,
                            const float* __restrict__ beta, const float* __restrict__ mean,
                            const float* __restrict__ var, const float* __restrict__ b1,
                            const float* __restrict__ b2, float* __restrict__ W2p,
                            float* __restrict__ c1, float* __restrict__ cbeta) {
    __shared__ float sc[64];
    __shared__ float sd[64];
    int t = threadIdx.x;
    if (t < 64) {
        float s = rsqrtf(var[t] + BN_EPS) * gamma[t];
        sc[t] = s;
        sd[t] = beta[t] - mean[t] * s;
    }
    __syncthreads();
    for (int i = t; i < 64 * OUT_DIM; i += 256) {
        int f = i / OUT_DIM;
        W2p[i] = sc[f] * W2[i];
    }
    if (t < WPAD) {
        if (t < OUT_DIM) {
            float acb = b2[t], ac1 = 0.f;
            for (int f = 0; f < 64; ++f) {
                float w2 = W2[f * OUT_DIM + t];
                acb = fmaf(sd[f], w2, acb);
                ac1 = fmaf(b1[f] * sc[f], w2, ac1);
            }
            cbeta[t] = acb;
            c1[t] = ac1;
        } else {
            c1[t] = 0.f;
        }
    }
}

__global__ __launch_bounds__(256) void wc_kernel(const float* __restrict__ W1,
                                                 const float* __restrict__ W2p,
                                                 float* __restrict__ Wc) {
    __shared__ float w2s[64 * OUT_DIM];
    for (int i = threadIdx.x; i < 64 * OUT_DIM; i += 256) w2s[i] = W2p[i];
    __syncthreads();
    int idx = blockIdx.x * 256 + threadIdx.x;
    if (idx >= IN_DIM * WPAD) return;
    int k = idx / WPAD, o = idx % WPAD;
    float a = 0.f;
    if (o < OUT_DIM) {
        const float* w1r = W1 + (size_t)k * HID;
#pragma unroll 8
        for (int f = 0; f < 64; ++f) a = fmaf(w1r[f], w2s[f * OUT_DIM + o], a);
    }
    Wc[idx] = a;
}

// ---------------- y0 = x @ Wc + c1 (register-staged software pipeline) -------
#define L1_M  128
#define L1_KC 20
#define L1_PITCH 132
__global__ __launch_bounds__(256) void lin1_kernel(const float* __restrict__ x,
                                                   const float* __restrict__ Wc,
                                                   const float* __restrict__ c1,
                                                   float* __restrict__ y0f,
                                                   unsigned* __restrict__ y0b) {
    __shared__ float xsT[L1_KC * L1_PITCH];
    __shared__ float wcs[L1_KC * WPAD];

    const int t = threadIdx.x;
    const int ng = t & 31;
    const int og = t >> 5;
    const int nbase = blockIdx.x * L1_M;

    const int srow = t >> 1;
    const int skb  = (t & 1) * 10;
    const int gsrc = nbase + srow;
    const int gcl  = (gsrc < N_NODES) ? gsrc : (N_NODES - 1);
    const float* xrow = x + (size_t)gcl * IN_DIM;

    float acc[4][6];
#pragma unroll
    for (int i = 0; i < 4; ++i)
#pragma unroll
        for (int j = 0; j < 6; ++j) acc[i][j] = 0.0f;

    // prologue: prefetch tile 0 into registers
    float2 xr[5];
    float wr[4];
#pragma unroll
    for (int u = 0; u < 5; ++u) xr[u] = *(const float2*)(xrow + skb + 2 * u);
#pragma unroll
    for (int j = 0; j < 4; ++j) {
        int i = t + j * 256;
        if (i < L1_KC * WPAD) wr[j] = Wc[i];
    }

    for (int k0 = 0; k0 < IN_DIM; k0 += L1_KC) {
        // drain staged registers into LDS
#pragma unroll
        for (int u = 0; u < 5; ++u) {
            xsT[(skb + 2 * u) * L1_PITCH + srow]     = xr[u].x;
            xsT[(skb + 2 * u + 1) * L1_PITCH + srow] = xr[u].y;
        }
#pragma unroll
        for (int j = 0; j < 4; ++j) {
            int i = t + j * 256;
            if (i < L1_KC * WPAD) wcs[i] = wr[j];
        }
        __syncthreads();

        // issue next tile's global loads; they fly under the FMA phase below
        const int kn = k0 + L1_KC;
        if (kn < IN_DIM) {
#pragma unroll
            for (int u = 0; u < 5; ++u) xr[u] = *(const float2*)(xrow + kn + skb + 2 * u);
#pragma unroll
            for (int j = 0; j < 4; ++j) {
                int i = t + j * 256;
                if (i < L1_KC * WPAD) wr[j] = Wc[(size_t)kn * WPAD + i];
            }
        }

#pragma unroll 4
        for (int k = 0; k < L1_KC; ++k) {
            const float4 xv = *(const float4*)&xsT[k * L1_PITCH + ng * 4];
            float w[6];
#pragma unroll
            for (int j = 0; j < 6; ++j) w[j] = wcs[k * WPAD + og * 6 + j];
            const float xr4[4] = {xv.x, xv.y, xv.z, xv.w};
#pragma unroll
            for (int i = 0; i < 4; ++i)
#pragma unroll
                for (int j = 0; j < 6; ++j)
                    acc[i][j] = fmaf(xr4[i], w[j], acc[i][j]);
        }
        __syncthreads();
    }

    float cc[6];
#pragma unroll
    for (int j = 0; j < 6; ++j) cc[j] = c1[og * 6 + j];
#pragma unroll
    for (int i = 0; i < 4; ++i) {
        const int n = nbase + ng * 4 + i;
        if (n < N_NODES) {
            float o[6];
#pragma unroll
            for (int j = 0; j < 6; ++j) o[j] = acc[i][j] + cc[j];
            // dims covered: og*6 .. og*6+5 ; only dims < 40 are stored
            float* yf = y0f + (size_t)n * YD + og * 6;
            unsigned* yb = y0b + (size_t)n * YH + og * 3;
            if (og < 6) {
                *(float2*)(yf)     = make_float2(o[0], o[1]);
                *(float2*)(yf + 2) = make_float2(o[2], o[3]);
                *(float2*)(yf + 4) = make_float2(o[4], o[5]);
                yb[0] = pack2(o[0], o[1]);
                yb[1] = pack2(o[2], o[3]);
                yb[2] = pack2(o[4], o[5]);
            } else if (og == 6) {   // dims 36..39 valid, 40..41 are pad
                *(float2*)(yf)     = make_float2(o[0], o[1]);
                *(float2*)(yf + 2) = make_float2(o[2], o[3]);
                yb[0] = pack2(o[0], o[1]);
                yb[1] = pack2(o[2], o[3]);
            }
            // og == 7: dims 42..47, all pad — nothing stored
        }
    }
}

// ---------------- APPNP step (40-dim, bf16 uint4 gather, fp32 accumulate) ----------
// 5 lanes per node (8 dims/lane via one uint4 = 8 bf16), 12 nodes per wave
// (60/64 lanes active), 4 waves per block -> 48 nodes/block.
// Edge segments are sorted by source eighth => gather working set stays L2-sized.
template <bool LAST>
__global__ __launch_bounds__(256) void appnp40_kernel(const int* __restrict__ rowptr,
                                                      const unsigned* __restrict__ ew,
                                                      const float* __restrict__ dinv,
                                                      const unsigned* __restrict__ yin,
                                                      const float* __restrict__ h,
                                                      unsigned* __restrict__ yout,
                                                      float* __restrict__ yKf) {
    const int wv   = threadIdx.x >> 6;      // wave 0..3
    const int lane = threadIdx.x & 63;
    const int sub  = lane / 5;              // 0..12 (12 -> inactive)
    const int dl   = lane - sub * 5;        // 0..4
    const int node = blockIdx.x * APG + wv * 12 + sub;
    const bool act = (lane < 60) && (node < N_NODES);
    const int dl4  = dl * 4;                // u32-word offset within row

    int beg = 0, end = 0;
    float selfw = 0.f;
    if (act) {
        beg = rowptr[node];
        end = rowptr[node + 1];
        const float di = dinv[node];
        selfw = di * di;
    }

    // issue the per-node loads early so they overlap the edge loop
    uint4 vs = make_uint4(0, 0, 0, 0);
    float4 h0 = make_float4(0.f, 0.f, 0.f, 0.f), h1 = h0;
    if (act) {
        vs = *(const uint4*)(yin + (size_t)node * YH + dl4);
        h0 = *(const float4*)(h + (size_t)node * YD + dl * 8);
        h1 = *(const float4*)(h + (size_t)node * YD + dl * 8 + 4);
    }

    float acc[8];
#pragma unroll
    for (int i = 0; i < 8; ++i) acc[i] = 0.f;

    int p = beg;
    for (; p + 3 < end; p += 4) {
        const unsigned e0 = ew[p], e1 = ew[p + 1], e2 = ew[p + 2], e3 = ew[p + 3];
        const uint4 v0 = *(const uint4*)(yin + (size_t)(e0 & 0x1ffff) * YH + dl4);
        const uint4 v1 = *(const uint4*)(yin + (size_t)(e1 & 0x1ffff) * YH + dl4);
        const uint4 v2 = *(const uint4*)(yin + (size_t)(e2 & 0x1ffff) * YH + dl4);
        const uint4 v3 = *(const uint4*)(yin + (size_t)(e3 & 0x1ffff) * YH + dl4);
        float f[8];
        unpack8(v0, f); fma8(acc, edge_w(e0), f);
        unpack8(v1, f); fma8(acc, edge_w(e1), f);
        unpack8(v2, f); fma8(acc, edge_w(e2), f);
        unpack8(v3, f); fma8(acc, edge_w(e3), f);
    }
    for (; p < end; ++p) {
        const unsigned e0 = ew[p];
        const uint4 v0 = *(const uint4*)(yin + (size_t)(e0 & 0x1ffff) * YH + dl4);
        float f[8];
        unpack8(v0, f);
        fma8(acc, edge_w(e0), f);
    }

    if (act) {
        float fs[8];
        unpack8(vs, fs);
        const float ha[8] = {h0.x, h0.y, h0.z, h0.w, h1.x, h1.y, h1.z, h1.w};
        float o[8];
#pragma unroll
        for (int i = 0; i < 8; ++i)
            o[i] = (1.0f - ALPHA) * fmaf(selfw, fs[i], acc[i]) + ALPHA * ha[i];
        if (LAST) {
            *(float4*)(yKf + (size_t)node * YD + dl * 8)     = make_float4(o[0], o[1], o[2], o[3]);
            *(float4*)(yKf + (size_t)node * YD + dl * 8 + 4) = make_float4(o[4], o[5], o[6], o[7]);
        } else {
            uint4 w;
            w.x = pack2(o[0], o[1]);
            w.y = pack2(o[2], o[3]);
            w.z = pack2(o[4], o[5]);
            w.w = pack2(o[6], o[7]);
            *(uint4*)(yout + (size_t)node * YH + dl4) = w;
        }
    }
}

// ---------------- emb = yK + cbeta; log_softmax ----------------
__global__ __launch_bounds__(256) void final_kernel(const float* __restrict__ yKf,
                                                    const float* __restrict__ cbeta,
                                                    float* __restrict__ out_ls,
                                                    float* __restrict__ out_emb) {
    const int lane = threadIdx.x & 63;
    const int wv   = threadIdx.x >> 6;
    const int node = blockIdx.x * 4 + wv;

    float e = 0.0f;
    if (lane < OUT_DIM) e = yKf[(size_t)node * YD + lane] + cbeta[lane];
    float ev = (lane < OUT_DIM) ? e : -INFINITY;
    float m = ev;
#pragma unroll
    for (int off = 32; off > 0; off >>= 1) m = fmaxf(m, __shfl_xor(m, off, 64));
    float p = (lane < OUT_DIM) ? expf(ev - m) : 0.0f;
    float s = p;
#pragma unroll
    for (int off = 32; off > 0; off >>= 1) s += __shfl_xor(s, off, 64);
    if (lane < OUT_DIM) {
        float ls = ev - m - logf(s);
        out_ls[(size_t)node * OUT_DIM + lane] = ls;
        out_emb[(size_t)node * OUT_DIM + lane] = e;
    }
}

// ---------------- launch ----------------

extern "C" void kernel_launch(void* const* d_in, const int* in_sizes, int n_in,
                              void* d_out, int out_size, void* d_ws, size_t ws_size,
                              hipStream_t stream) {
    const float* x     = (const float*)d_in[0];
    const int*   ei    = (const int*)d_in[1];
    const float* W1    = (const float*)d_in[2];
    const float* b1    = (const float*)d_in[3];
    const float* gamma = (const float*)d_in[4];
    const float* beta  = (const float*)d_in[5];
    const float* mean  = (const float*)d_in[6];
    const float* var   = (const float*)d_in[7];
    const float* W2    = (const float*)d_in[8];
    const float* b2    = (const float*)d_in[9];

    char* ws = (char*)d_ws;
    size_t off = 0;
    auto alloc = [&](size_t bytes) { char* p = ws + off; off += (bytes + 255) & ~(size_t)255; return p; };

    unsigned* ew     = (unsigned*)alloc((size_t)N_EDGES * 4);          // 12.8 MB
    unsigned* ebuf   = (unsigned*)alloc((size_t)N_EDGES * 4);          // 12.8 MB
    float*    y0f    = (float*)   alloc((size_t)N_NODES * YD * 4);     // 16 MB
    float*    yKf    = (float*)   alloc((size_t)N_NODES * YD * 4);     // 16 MB
    unsigned* y0b    = (unsigned*)alloc((size_t)N_NODES * YH * 4);     // 8 MB
    unsigned* ya     = (unsigned*)alloc((size_t)N_NODES * YH * 4);
    unsigned* yb     = (unsigned*)alloc((size_t)N_NODES * YH * 4);
    float*    Wc     = (float*)   alloc((size_t)IN_DIM * WPAD * 4);
    float*    W2p    = (float*)   alloc(64 * OUT_DIM * 4);
    float*    c1     = (float*)   alloc(WPAD * 4);
    float*    cbeta  = (float*)   alloc(OUT_DIM * 4);
    int*      cntq   = (int*)     alloc((size_t)NQ * N_NODES * 4);     // 3.2 MB
    float*    dinv   = (float*)   alloc(N_NODES * 4);
    int*      rowptr = (int*)     alloc((N_NODES + 1) * 4);
    int*      bcursor= (int*)     alloc(NBUCK * 4);
    int*      psum   = (int*)     alloc(1600 * 4);
    int*      pexcl  = (int*)     alloc(1600 * 4);

    float* out_ls  = (float*)d_out;
    float* out_emb = (float*)d_out + (size_t)N_NODES * OUT_DIM;

    const int NB_N = (N_NODES + 255) / 256;   // 391
    const int NB_E = (N_EDGES + 255) / 256;   // 12500
    const int NB_A = (N_EDGES + TILE_A - 1) / TILE_A;  // 391
    const int NB_P = (N_NODES + APG - 1) / APG;        // 2084
    const int NB_Z = (NQ * N_NODES + 255) / 256;       // 3125

    zero_cnt_kernel<<<NB_Z, 256, 0, stream>>>(cntq);
    hist_kernel<<<NB_E, 256, 0, stream>>>(ei, cntq);
    reduce_kernel<<<NB_N, 256, 0, stream>>>(cntq, psum);
    scanp_kernel<<<1, 512, 0, stream>>>(psum, pexcl, NB_N);
    apply_kernel<<<NB_N, 256, 0, stream>>>(cntq, pexcl, rowptr, dinv);
    bcur_init_kernel<<<(NBUCK + 255) / 256, 256, 0, stream>>>(rowptr, bcursor);
    bucketA_kernel<<<NB_A, 256, 0, stream>>>(ei, bcursor, ebuf);
    bucketB_kernel<<<NBUCK, 256, 0, stream>>>(ebuf, rowptr, cntq, dinv, ew);

    prep_kernel<<<1, 256, 0, stream>>>(W2, gamma, beta, mean, var, b1, b2, W2p, c1, cbeta);
    wc_kernel<<<(IN_DIM * WPAD + 255) / 256, 256, 0, stream>>>(W1, W2p, Wc);
    lin1_kernel<<<(N_NODES + L1_M - 1) / L1_M, 256, 0, stream>>>(x, Wc, c1, y0f, y0b);

    const unsigned* cur = y0b;
    unsigned* nxt = ya;
    unsigned* buf[2] = {ya, yb};
    for (int k = 0; k < K_ITERS - 1; ++k) {
        appnp40_kernel<false><<<NB_P, 256, 0, stream>>>(rowptr, ew, dinv, cur,
                                                        y0f, nxt, nullptr);
        cur = nxt;
        nxt = buf[(k + 1) & 1];
    }
    appnp40_kernel<true><<<NB_P, 256, 0, stream>>>(rowptr, ew, dinv, cur,
                                                   y0f, nullptr, yKf);

    final_kernel<<<N_NODES / 4, 256, 0, stream>>>(yKf, cbeta, out_ls, out_emb);
}